// Round 4
// baseline (167.161 us; speedup 1.0000x reference)
//
#include <hip/hip_runtime.h>

// SSIM loss v11: restore branchless step body (the v7 property that mattered).
// Evidence: per wave-step cycles -- v7 (3 w/SIMD, branchless selects) = 773;
// v9 (6 w/SIMD, branchy loads) = 859; v10 (3 w/SIMD, branchy loads) = 864.
// Occupancy was irrelevant; the uniform `if (row ok)` around the loads pinned
// load+mask-mul in one small block => immediate vmcnt wait each step. v11
// makes the whole step body a single basic block again:
//  - LOADROW via uniform selects (row clamp + row-mask select), no branch.
//  - staging write unguarded: buffer widened to 128 pairs, lanes 38..63
//    write zero-masked values into never-read slots (no exec toggle).
//  - retire computed unconditionally, accumulated via fmaf with uniform gate.
// Kept from v10: float2 loads (2/step), 1 ds_write_b128, distance-2 prefetch,
// rcp retire, k=0 peel, slot-9 product fold (10-slot ring).
// Predicted: VALUBusy 47->60-70%, kernel 80 -> ~55-65us, WRITE ~24KB.

#define BATCH  16
#define CHAN   3
#define H_     512
#define W_     512
#define HW     (H_ * W_)
#define CH_H   64
#define NSTEP  (CH_H + 10)          // 74 = 37 * 2
#define NPIX   ((long)BATCH*CHAN*H_*W_)

// Normalized 11-tap Gaussian, sigma=1.5 (constants gave absmax 0 in v1/v2/v6).
#define GW0 0.0010284f
#define GW1 0.0075988f
#define GW2 0.0360008f
#define GW3 0.1093554f
#define GW4 0.2130056f
#define GW5 0.2660117f

typedef float v2  __attribute__((ext_vector_type(2)));
typedef float v4f __attribute__((ext_vector_type(4)));

__device__ __forceinline__ float wg(int k) {  // k literal -> folds to constant
    return (k == 0 || k == 10) ? GW0
         : (k == 1 || k == 9)  ? GW1
         : (k == 2 || k == 8)  ? GW2
         : (k == 3 || k == 7)  ? GW3
         : (k == 4 || k == 6)  ? GW4 : GW5;
}

__device__ __forceinline__ v2 pfma(v2 a, v2 b, v2 c) {
#if __has_builtin(__builtin_elementwise_fma)
    return __builtin_elementwise_fma(a, b, c);
#else
    v2 r; r.x = fmaf(a.x, b.x, c.x); r.y = fmaf(a.y, b.y, c.y); return r;
#endif
}
__device__ __forceinline__ v2 psfma(float s, v2 b, v2 c) {  // (s,s)*b + c
    v2 sv; sv.x = s; sv.y = s;
    return pfma(sv, b, c);
}

__device__ __forceinline__ float ssim_retire(float mu1, float mu2,
                                             float x11, float x22, float x12) {
    const float c1 = 1.0e-4f;
    const float c2 = 9.0e-4f;
    float mu1s = mu1 * mu1;
    float mu2s = mu2 * mu2;
    float m12  = mu1 * mu2;
    float num  = (2.0f * m12 + c1) * (2.0f * (x12 - m12) + c2);
    float den  = (mu1s + mu2s + c1) * ((x11 - mu1s) + (x22 - mu2s) + c2);
#if __has_builtin(__builtin_amdgcn_rcpf)
    float l = 1.0f - num * __builtin_amdgcn_rcpf(den);   // v_rcp_f32, ~1 ulp
#else
    float l = 1.0f - num / den;
#endif
    return fminf(fmaxf(l, 0.0f), 1.0f);
}

// Slot i state: P=(mu1,mu2) packed, Q=(x11,x22) packed, E=x12 scalar.
#define DECL(i) v2 P##i = {0.f, 0.f}, Q##i = {0.f, 0.f}; float E##i = 0.f
#define ACCI(i) do { const float wj_ = wg(10 - (i));             \
    P##i = psfma(wj_, hmm, P##i);                                \
    Q##i = psfma(wj_, hss, Q##i);                                \
    E##i = fmaf(wj_, hm12, E##i); } while (0)
#define SHIFT(i, j) P##i = P##j; Q##i = Q##j; E##i = E##j

// Branchless padded-row load: uniform row clamp + select, per-lane col mask.
// No control flow => stays inside the step's single basic block, letting the
// scheduler hoist the loads and sink the mask-muls (cross-step slack).
#define LOADROW(r_, da_, db_) do {                                 \
    int rr_ = (r_);                                                \
    bool rok_ = (unsigned)rr_ < (unsigned)H_;   /* uniform */      \
    size_t off_ = ((size_t)(rok_ ? rr_ : 0) << 9) + cix;           \
    v2 a_ = *(const v2*)(p1 + off_);                               \
    v2 b_ = *(const v2*)(p2 + off_);                               \
    float m_ = rok_ ? msk : 0.0f;                                  \
    da_ = a_ * m_; db_ = b_ * m_; } while (0)

__global__ __launch_bounds__(256) void ssim_kernel(const float* __restrict__ img1,
                                                   const float* __restrict__ img2,
                                                   float* __restrict__ out) {
    // Per-wave double-buffered staging; 128 pairs/buffer so all 64 lanes can
    // write unconditionally (slots 76..127 are zero-filled, never read).
    __shared__ __align__(16) v2 sp[4][2][128];
    __shared__ float wsum[4];

    const int tid  = threadIdx.x;
    const int lane = tid & 63;
    const int wv   = tid >> 6;

    const int wid   = blockIdx.x * 4 + wv;     // 0..3071
    const int plane = wid >> 6;                // 48 planes
    const int rem   = wid & 63;
    const int strip = rem & 7;
    const int chunk = rem >> 3;                // 0..7
    const int y0 = chunk * CH_H;
    const int c0 = strip * 64;

    // Lane L (<38) owns col pair (c0-6+2L, c0-6+2L+1) of both images.
    // Pairs are fully in- or out-of-range (edges are multiples of 2), so one
    // mask per lane; OOB/idle lanes read clamped addr then multiply by 0.
    const int  cg   = c0 - 6 + 2 * lane;
    const bool cok  = (cg >= 0) && (cg < W_) && (lane < 38);
    const int  cix  = cok ? cg : 0;
    const float msk = cok ? 1.0f : 0.0f;

    const size_t pb = (size_t)plane * HW;
    const float* __restrict__ p1 = img1 + pb;   // wave-uniform bases
    const float* __restrict__ p2 = img2 + pb;

    v2 (*st)[128] = sp[wv];

    DECL(0); DECL(1); DECL(2); DECL(3); DECL(4);
    DECL(5); DECL(6); DECL(7); DECL(8); DECL(9);
    float lsum = 0.0f;

    // Two rows in flight: R0 = row staged this step, R1 = next row.
    v2 r0a, r0b, r1a, r1b;
    LOADROW(y0 - 5, r0a, r0b);
    LOADROW(y0 - 4, r1a, r1b);

#pragma unroll 1
    for (int sb = 0; sb < NSTEP / 2; ++sb) {
#pragma unroll
        for (int j = 0; j < 2; ++j) {
            const int step = sb * 2 + j;
            const int par  = j;                 // compile-time buffer parity

            // 1. Issue loads for row step+2 (2 compute phases of slack).
            v2 r2a, r2b;
            LOADROW(y0 + step - 3, r2a, r2b);

            // 2. Stage row R0: {a0,b0,a1,b1} as one ds_write_b128, all lanes.
            {
                v4f w; w.x = r0a.x; w.y = r0b.x; w.z = r0a.y; w.w = r0b.y;
                *(v4f*)&st[par][2 * lane] = w;
            }
            __asm__ __volatile__("" ::: "memory");  // writes before reads

            // 3. Horizontal 11-tap, packed: hmm=(m1,m2), hss=(m11,m22), hm12.
            //    k=0 peeled (init by product, no zero-init adds).
            v2 ab0 = st[par][lane + 1];
            v2 hmm = ab0 * wg(0);               // pk_mul
            v2 hss = hmm * ab0;                 // pk_mul
            float hm12 = hmm.x * ab0.y;
#pragma unroll
            for (int k = 1; k < 11; ++k) {
                v2 ab = st[par][lane + 1 + k];  // ds_read_b64, imm offset
                float wk = wg(k);
                v2 t = ab;
                t.x *= wk; t.y *= wk;           // pk_mul (t1,t2)
                hmm += t;                       // pk_add
                hss = pfma(t, ab, hss);         // pk_fma -> (m11,m22)
                hm12 = fmaf(t.x, ab.y, hm12);   // scalar cross term
            }

            // 4. Accumulate into in-flight rows 0..9 (fresh slot folded below).
            ACCI(0); ACCI(1); ACCI(2); ACCI(3); ACCI(4);
            ACCI(5); ACCI(6); ACCI(7); ACCI(8); ACCI(9);

            // 5. Retire slot 0 unconditionally; uniform float gate (no branch).
            {
                float l0 = ssim_retire(P0.x, P0.y, Q0.x, Q0.y, E0);
                float g  = (step >= 10) ? 1.0f : 0.0f;
                lsum = fmaf(g, l0, lsum);
            }

            // 6. Shift ring; fresh slot 9 is a direct product (weight wg(0)).
            SHIFT(0, 1); SHIFT(1, 2); SHIFT(2, 3); SHIFT(3, 4); SHIFT(4, 5);
            SHIFT(5, 6); SHIFT(6, 7); SHIFT(7, 8); SHIFT(8, 9);
            P9 = hmm * wg(0); Q9 = hss * wg(0); E9 = hm12 * wg(0);

            // 7. Advance the row pipeline (renames away under unroll-2).
            r0a = r1a; r0b = r1b; r1a = r2a; r1b = r2b;
        }
    }

    // Reduction: wave shuffle -> LDS -> one atomic per block.
#pragma unroll
    for (int off = 32; off > 0; off >>= 1) lsum += __shfl_down(lsum, off);
    if (lane == 0) wsum[wv] = lsum;
    __syncthreads();
    if (tid == 0) {
        float bs = wsum[0] + wsum[1] + wsum[2] + wsum[3];
        atomicAdd(out, bs * (0.5f / (float)NPIX));
    }
}

extern "C" void kernel_launch(void* const* d_in, const int* in_sizes, int n_in,
                              void* d_out, int out_size, void* d_ws, size_t ws_size,
                              hipStream_t stream) {
    const float* img1 = (const float*)d_in[0];
    const float* img2 = (const float*)d_in[1];
    float* out = (float*)d_out;

    hipMemsetAsync(out, 0, sizeof(float), stream);

    // 8 strips x 8 chunks x 48 planes = 3072 waves = 768 blocks = 3/CU.
    ssim_kernel<<<dim3(8 * 8 * BATCH * CHAN / 4), 256, 0, stream>>>(img1, img2, out);
}

// Round 5
// 153.258 us; speedup vs baseline: 1.0907x; 1.0907x over previous
//
#include <hip/hip_runtime.h>

// SSIM loss v12: exact v7 body + rcp retire. Re-anchor round.
// Cross-round evidence (cyc per wave-step per SIMD): v7=773 (VALU 466),
// v9=862 (414, 6 waves/SIMD), v10=864 (415), v11=876 (420).
//  - v9 at 2x occupancy matched v10's per-CU throughput exactly: CU-saturated,
//    occupancy is not the lever.
//  - v10/v11 run 11% fewer VALU cycles than v7 yet 13% slower: instruction
//    count is not the lever either. The float2/b128/distance-2 restaging
//    degraded the compiler's software pipeline and 3 fixes failed to recover.
// => keep v7's byte-identical body (scalar 64-lane loads, 2x ds_write_b64,
//    two fences, distance-1 prefetch, 11-slot ring, unroll 2) and change ONLY
//    the retire division to v_rcp_f32 (local to epilogue, schedule-neutral).
// Predicted: VALUBusy 60->57-59%, kernel 71.5 -> ~68-69.5us.

#define BATCH  16
#define CHAN   3
#define H_     512
#define W_     512
#define HW     (H_ * W_)
#define CH_H   64
#define NPIX   ((long)BATCH*CHAN*H_*W_)

// Normalized 11-tap Gaussian, sigma=1.5 (constants gave absmax 0 in v1/v2/v6).
#define GW0 0.0010284f
#define GW1 0.0075988f
#define GW2 0.0360008f
#define GW3 0.1093554f
#define GW4 0.2130056f
#define GW5 0.2660117f

typedef float v2 __attribute__((ext_vector_type(2)));

__device__ __forceinline__ float wg(int k) {  // k literal -> folds to constant
    return (k == 0 || k == 10) ? GW0
         : (k == 1 || k == 9)  ? GW1
         : (k == 2 || k == 8)  ? GW2
         : (k == 3 || k == 7)  ? GW3
         : (k == 4 || k == 6)  ? GW4 : GW5;
}

__device__ __forceinline__ v2 pfma(v2 a, v2 b, v2 c) {
#if __has_builtin(__builtin_elementwise_fma)
    return __builtin_elementwise_fma(a, b, c);
#else
    v2 r; r.x = fmaf(a.x, b.x, c.x); r.y = fmaf(a.y, b.y, c.y); return r;
#endif
}
__device__ __forceinline__ v2 psfma(float s, v2 b, v2 c) {  // (s,s)*b + c
    v2 sv; sv.x = s; sv.y = s;
    return pfma(sv, b, c);
}

__device__ __forceinline__ float ssim_retire(float mu1, float mu2,
                                             float x11, float x22, float x12) {
    const float c1 = 1.0e-4f;
    const float c2 = 9.0e-4f;
    float mu1s = mu1 * mu1;
    float mu2s = mu2 * mu2;
    float m12  = mu1 * mu2;
    float num  = (2.0f * m12 + c1) * (2.0f * (x12 - m12) + c2);
    float den  = (mu1s + mu2s + c1) * ((x11 - mu1s) + (x22 - mu2s) + c2);
#if __has_builtin(__builtin_amdgcn_rcpf)
    float l = 1.0f - num * __builtin_amdgcn_rcpf(den);   // v_rcp_f32, ~1 ulp
#else
    float l = 1.0f - num / den;
#endif
    return fminf(fmaxf(l, 0.0f), 1.0f);
}

// Slot i state: P=(mu1,mu2) packed, Q=(x11,x22) packed, E=x12 scalar.
#define DECL(i) v2 P##i = {0.f, 0.f}, Q##i = {0.f, 0.f}; float E##i = 0.f
#define ACCI(i) do { const float wj_ = wg(10 - (i));             \
    P##i = psfma(wj_, hmm, P##i);                                \
    Q##i = psfma(wj_, hss, Q##i);                                \
    E##i = fmaf(wj_, hm12, E##i); } while (0)
#define SHIFT(i, j) P##i = P##j; Q##i = Q##j; E##i = E##j

__global__ __launch_bounds__(256, 3) void ssim_kernel(const float* __restrict__ img1,
                                                      const float* __restrict__ img2,
                                                      float* __restrict__ out) {
    __shared__ __align__(16) v2 sp[4][80];   // interleaved (img1,img2), 75 used
    __shared__ float wsum[4];

    const int tid  = threadIdx.x;
    const int lane = tid & 63;
    const int wv   = tid >> 6;

    const int wid   = blockIdx.x * 4 + wv;     // 0..3071
    const int plane = wid >> 6;
    const int rem   = wid & 63;
    const int strip = rem & 7;
    const int chunk = rem >> 3;
    const int y0 = chunk * CH_H;
    const int c0 = strip * 64;

    // sp[i] <-> cols c0-5+i of (img1, img2), i = 0..74.
    const int  colg  = c0 - 5 + lane;          // only <0 can be OOB (max 507)
    const bool colOk = (colg >= 0);
    const int  colC  = colOk ? colg : 0;
    const int  colg2  = c0 + 59 + lane;        // halo cols, lanes 0..10
    const bool colOk2 = (lane < 11) && (colg2 < W_);
    const int  col2C  = colOk2 ? colg2 : 0;

    const size_t pb = (size_t)plane * HW;
    const float* __restrict__ p1  = img1 + pb + colC;
    const float* __restrict__ p2  = img2 + pb + colC;
    const float* __restrict__ p1b = img1 + pb + col2C;
    const float* __restrict__ p2b = img2 + pb + col2C;

    v2* st = sp[wv];

    DECL(0); DECL(1); DECL(2); DECL(3); DECL(4); DECL(5);
    DECL(6); DECL(7); DECL(8); DECL(9); DECL(10);
    float lsum = 0.0f;

    // Preload first h-row (r = y0 - 5; zero if OOB -> matches zero padding).
    float cv1, cv2, cv1b, cv2b;
    {
        int r = y0 - 5;
        bool rok = (unsigned)r < (unsigned)H_;
        size_t off = (size_t)(rok ? r : 0) * W_;
        cv1  = (rok && colOk)  ? p1[off]  : 0.0f;
        cv2  = (rok && colOk)  ? p2[off]  : 0.0f;
        cv1b = (rok && colOk2) ? p1b[off] : 0.0f;
        cv2b = (rok && colOk2) ? p2b[off] : 0.0f;
    }

#pragma unroll 2
    for (int step = 0; step < 74; ++step) {
        const int yy = step - 10;              // output row retired this step

        // 1. Stage current h-row (75 interleaved col-pairs).
        {
            v2 v; v.x = cv1; v.y = cv2;
            st[lane] = v;
            if (lane < 11) { v2 vb; vb.x = cv1b; vb.y = cv2b; st[64 + lane] = vb; }
        }
        __asm__ __volatile__("" ::: "memory");   // writes complete before reads

        // 2. Prefetch next h-row (r = y0 + yy + 6); independent of this step.
        {
            int r = y0 + yy + 6;
            bool rok = (unsigned)r < (unsigned)H_;
            size_t off = (size_t)(rok ? r : 0) * W_;
            cv1  = (rok && colOk)  ? p1[off]  : 0.0f;
            cv2  = (rok && colOk)  ? p2[off]  : 0.0f;
            cv1b = (rok && colOk2) ? p1b[off] : 0.0f;
            cv2b = (rok && colOk2) ? p2b[off] : 0.0f;
        }

        // 3. Horizontal 11-tap, packed: hmm=(m1,m2), hss=(m11,m22), hm12.
        v2 hmm = {0.f, 0.f}, hss = {0.f, 0.f};
        float hm12 = 0.f;
#pragma unroll
        for (int k = 0; k < 11; ++k) {
            v2 ab = st[lane + k];              // ds_read_b64
            float wk = wg(k);
            v2 t = ab;
            t.x *= wk; t.y *= wk;              // pk_mul (t1,t2)
            hmm += t;                          // pk_add
            hss = pfma(t, ab, hss);            // pk_fma -> (m11,m22)
            hm12 = fmaf(t.x, ab.y, hm12);      // scalar cross term
        }
        __asm__ __volatile__("" ::: "memory");   // next iter's writes stay after reads

        // 4. Accumulate into the 11 in-flight output rows.
        ACCI(0); ACCI(1); ACCI(2); ACCI(3); ACCI(4); ACCI(5);
        ACCI(6); ACCI(7); ACCI(8); ACCI(9); ACCI(10);

        // 5. Retire output row yy (slot 0 complete).
        if (yy >= 0) lsum += ssim_retire(P0.x, P0.y, Q0.x, Q0.y, E0);

        // 6. Shift the register ring (pure SSA renames; unroll-2 elides half).
        SHIFT(0, 1); SHIFT(1, 2); SHIFT(2, 3); SHIFT(3, 4); SHIFT(4, 5);
        SHIFT(5, 6); SHIFT(6, 7); SHIFT(7, 8); SHIFT(8, 9); SHIFT(9, 10);
        P10 = (v2){0.f, 0.f}; Q10 = (v2){0.f, 0.f}; E10 = 0.f;
    }

    // Reduction: wave shuffle -> LDS -> one atomic per block.
#pragma unroll
    for (int off = 32; off > 0; off >>= 1) lsum += __shfl_down(lsum, off);
    if (lane == 0) wsum[wv] = lsum;
    __syncthreads();
    if (tid == 0) {
        float bs = wsum[0] + wsum[1] + wsum[2] + wsum[3];
        atomicAdd(out, bs * (0.5f / (float)NPIX));
    }
}

extern "C" void kernel_launch(void* const* d_in, const int* in_sizes, int n_in,
                              void* d_out, int out_size, void* d_ws, size_t ws_size,
                              hipStream_t stream) {
    const float* img1 = (const float*)d_in[0];
    const float* img2 = (const float*)d_in[1];
    float* out = (float*)d_out;

    hipMemsetAsync(out, 0, sizeof(float), stream);

    ssim_kernel<<<dim3(8 * 8 * BATCH * CHAN / 4), 256, 0, stream>>>(img1, img2, out);
}